// Round 19
// baseline (79.839 us; speedup 1.0000x reference)
//
#include <hip/hip_runtime.h>
#include <hip/hip_bf16.h>

// NCE / NT-Xent loss, B=4096, D=256, temp=0.5.
// loss = mean_i( log(sum_{j!=i} exp(sim_ij)) - sim_{i,(i+B)%N} ), N=8192.
// |sim| <= 2 => exp(sim) <= e^2: plain sum(exp), no online max.
//
// R19: accumulator-dominant GEMM (m201/m225 pattern) + symmetry.
//   Root cause R5-R18: compiler always sinks/remats persistent A-operand
//   registers -> L1 reload storm (~2560 cyc/tile/CU). Fix: NO persistent
//   operand regs. acc[8][4] (128 VGPR) is the only long-lived state --
//   accumulators cannot be rematerialized. Both A and B slices stream
//   through rotating LDS (3 bufs x 32KB), R17-proven counted-vmcnt
//   schedule. exp + dual-axis fold run ONCE per block in the epilogue.
//   Triangular 256x256 supertile grid (528 blocks = 51.5% of full work);
//   square tiles => mirror-fold rule is simply offDiag-or-not.
// Algebraic offload (R14): diag stays in row sums, k_final subtracts
//   exp2(||zhat||^2 scaled); pos computed by k_pos as row-pair dots.
//
// Zn stored scaled by sqrt(2*log2(e)) so MFMA output IS the exp2 argument.
// Fragment-tiled Zn: 16-row group g, element (g*16+rr, d), ks=d>>5,
// lhi=(d>>3)&3, dlo=d&7 -> zn[g*4096 + ks*512 + lhi*128 + rr*8 + dlo];
// lane l's fragment ks of group g = 16B at zn + g*4096 + ks*512 + l*8.

constexpr int kN  = 8192;        // 2B rows
constexpr int kD  = 256;         // embedding dim
constexpr int kBH = 4096;        // B
constexpr int kST = 256;         // supertile edge
constexpr int kNRT = kN / kST;   // 32 supertile rows
constexpr int kGrid = kNRT * (kNRT + 1) / 2;   // 528 triangular blocks
constexpr int kKS = kD / 32;     // 8 K-steps (BK=32)
constexpr float kSqrtScale = 1.6986436f;  // sqrt(2*log2(e))
constexpr float kLn2 = 0.6931471805599453f;

typedef __attribute__((ext_vector_type(8))) short bf16x8;  // 4 VGPRs
typedef __attribute__((ext_vector_type(4))) float f32x4;

__device__ __forceinline__ unsigned short f2bf(float f) {
  union { float f; unsigned u; } x;
  x.f = f;
  unsigned u = x.u;
  return (unsigned short)((u + 0x7FFFu + ((u >> 16) & 1u)) >> 16);
}
__device__ __forceinline__ float bf2f(unsigned short h) {
  union { unsigned u; float f; } x;
  x.u = ((unsigned)h) << 16;
  return x.f;
}
__device__ __forceinline__ void gload_lds16(const short* g, short* l) {
  __builtin_amdgcn_global_load_lds(
      (const __attribute__((address_space(1))) void*)g,
      (__attribute__((address_space(3))) void*)l, 16, 0, 0);
}

// ---------------- kernel 1: row-normalize fp32 -> bf16 (tiled + scaled) ---
// Blocks 0..7 zero s_sum; stream order guarantees completion before k_simlse.
__global__ void k_normalize(const float* __restrict__ e1,
                            const float* __restrict__ e2,
                            unsigned short* __restrict__ zn,
                            float* __restrict__ s_sum) {
  if (blockIdx.x < 8) {
    float4 z4 = {0.f, 0.f, 0.f, 0.f};
    *reinterpret_cast<float4*>(s_sum + blockIdx.x * 1024 + threadIdx.x * 4) = z4;
  }
  const int wave = threadIdx.x >> 6;
  const int lane = threadIdx.x & 63;
  const int row  = blockIdx.x * 4 + wave;
  const float* src = (row < kBH) ? (e1 + (size_t)row * kD)
                                 : (e2 + (size_t)(row - kBH) * kD);
  float4 v = *reinterpret_cast<const float4*>(src + lane * 4);
  float ssq = v.x * v.x + v.y * v.y + v.z * v.z + v.w * v.w;
#pragma unroll
  for (int m = 1; m < 64; m <<= 1) ssq += __shfl_xor(ssq, m);
  const float invs = kSqrtScale / sqrtf(ssq);   // eps can never bind (|z|~16)
  ushort4 o;
  o.x = f2bf(v.x * invs);
  o.y = f2bf(v.y * invs);
  o.z = f2bf(v.z * invs);
  o.w = f2bf(v.w * invs);
  const int g  = row >> 4;
  const int rr = row & 15;
  const size_t dst = (size_t)g * 4096 + (lane >> 3) * 512 +
                     ((lane >> 1) & 3) * 128 + rr * 8 + (lane & 1) * 4;
  *reinterpret_cast<ushort4*>(zn + dst) = o;
}

// ---------------- kernel 1b: row-pair dots (pos + diag), 1 wave/pair ------
__global__ void k_pos(const unsigned short* __restrict__ zn,
                      float* __restrict__ pos_val,
                      float* __restrict__ dacc) {
  const int wave = threadIdx.x >> 6;
  const int lane = threadIdx.x & 63;
  const int i = blockIdx.x * 4 + wave;        // 0..4095
  const int j = i + kBH;
  const int rr = i & 15;
  const size_t off = (size_t)(i >> 4) * 4096 + (lane >> 3) * 512 +
                     ((lane >> 1) & 3) * 128 + rr * 8 + (lane & 1) * 4;
  ushort4 ua = *reinterpret_cast<const ushort4*>(zn + off);
  ushort4 ub = *reinterpret_cast<const ushort4*>(zn + off + (size_t)256 * 4096);
  float dij = 0.f, dii = 0.f, djj = 0.f;
  const unsigned short* pa = &ua.x;
  const unsigned short* pb = &ub.x;
#pragma unroll
  for (int q = 0; q < 4; ++q) {
    const float a = bf2f(pa[q]);
    const float b = bf2f(pb[q]);
    dij += a * b;
    dii += a * a;
    djj += b * b;
  }
#pragma unroll
  for (int m = 1; m < 64; m <<= 1) {
    dij += __shfl_xor(dij, m);
    dii += __shfl_xor(dii, m);
    djj += __shfl_xor(djj, m);
  }
  if (lane == 0) {
    const float p = dij * kLn2;   // scaled-dot * ln2 == sim/temp
    pos_val[i] = p;
    pos_val[j] = p;
    dacc[i] = dii;
    dacc[j] = djj;
  }
}

// ---------------- kernel 2: triangular acc-GEMM + exp + dual fold ---------
// Grid: 528 blocks (supertile pairs rt>=ct). Block: 512 thr = 8 waves (2x4);
// wave-tile 128x64 -> acc[8][4] f32x4 (128 VGPR). K-loop: 8 steps of BK=32;
// A-slice + B-slice (16KB each) staged into 3 rotating LDS buffers with
// { vmcnt(4); barrier; stage(kk+2); compute(kk) } (counted, never 0).
__global__ __launch_bounds__(512, 2)
void k_simlse(const unsigned short* __restrict__ zn,
              float* __restrict__ s_sum) {
  __shared__ __align__(16) short ldsA[3][8192];   // 3 x 16KB A K-slices
  __shared__ __align__(16) short ldsB[3][8192];   // 3 x 16KB B K-slices

  // triangular decode: rt = row supertile, ct <= rt
  const int bid = blockIdx.x;
  int rt = (int)((sqrtf(8.0f * bid + 1.0f) - 1.0f) * 0.5f);
  while ((rt + 1) * (rt + 2) / 2 <= bid) ++rt;
  while (rt * (rt + 1) / 2 > bid) --rt;
  const int ct = bid - rt * (rt + 1) / 2;
  const bool offDiag = (rt != ct);

  const int tid = threadIdx.x;
  const int wave = tid >> 6;      // 0..7
  const int wr = wave >> 2;       // 0..1  row half
  const int wc = wave & 3;        // 0..3  col quarter
  const int lane = tid & 63;
  const int l15 = lane & 15;
  const int lhi = lane >> 4;
  const int rowSup = rt * kST;
  const int colSup = ct * kST;
  const int gA = (rowSup >> 4);   // first 16-row group of A panel
  const int gB = (colSup >> 4);   // first 16-row group of B panel

  // Stage K-step kk (ks = kk&7) into buffer kk%3. Each wave copies 4KB:
  // A groups {wave, wave+8} and B groups {wave, wave+8}, 1KB each.
  auto stage = [&](int kk) {
    const int ks = kk & 7;
    const int buf = kk % 3;
    const short* zs = (const short*)zn;
    gload_lds16(zs + (size_t)(gA + wave) * 4096 + ks * 512 + lane * 8,
                &ldsA[buf][wave * 512 + lane * 8]);
    gload_lds16(zs + (size_t)(gA + 8 + wave) * 4096 + ks * 512 + lane * 8,
                &ldsA[buf][(8 + wave) * 512 + lane * 8]);
    gload_lds16(zs + (size_t)(gB + wave) * 4096 + ks * 512 + lane * 8,
                &ldsB[buf][wave * 512 + lane * 8]);
    gload_lds16(zs + (size_t)(gB + 8 + wave) * 4096 + ks * 512 + lane * 8,
                &ldsB[buf][(8 + wave) * 512 + lane * 8]);
  };

  f32x4 acc[8][4];
#pragma unroll
  for (int g = 0; g < 8; ++g)
#pragma unroll
    for (int c = 0; c < 4; ++c) acc[g][c] = {0.f, 0.f, 0.f, 0.f};

  stage(0);
  stage(1);
  asm volatile("s_waitcnt vmcnt(0)" ::: "memory");   // exact in-loop counting

#pragma unroll 1
  for (int kk = 0; kk < kKS; ++kk) {
    // own outstanding at top (steady): stage(kk)+stage(kk+1) = 8; wait kk.
    asm volatile("s_waitcnt vmcnt(4)" ::: "memory");
    __builtin_amdgcn_s_barrier();   // all waves have K-slice kk; all done
                                    // reading the buffer stage(kk+2) reuses
    stage(kk + 2);                  // dead wrap at kk>=6 (harmless)

    const short* pA = &ldsA[kk % 3][0];
    const short* pB = &ldsB[kk % 3][0];
    bf16x8 bfr[4];
#pragma unroll
    for (int c = 0; c < 4; ++c)
      bfr[c] = *reinterpret_cast<const bf16x8*>(pB + (wc * 4 + c) * 512 + lane * 8);
    __builtin_amdgcn_s_setprio(1);
#pragma unroll
    for (int g = 0; g < 8; ++g) {
      const bf16x8 afr =
          *reinterpret_cast<const bf16x8*>(pA + (wr * 8 + g) * 512 + lane * 8);
#pragma unroll
      for (int c = 0; c < 4; ++c)
        acc[g][c] = __builtin_amdgcn_mfma_f32_16x16x32_bf16(afr, bfr[c], acc[g][c], 0, 0, 0);
    }
    __builtin_amdgcn_s_setprio(0);
  }

  // ---- epilogue (once): exp2, row fold (always), col fold (offDiag) ----
  float csum[4] = {0.f, 0.f, 0.f, 0.f};
#pragma unroll
  for (int g = 0; g < 8; ++g) {
    float rs[4] = {0.f, 0.f, 0.f, 0.f};
#pragma unroll
    for (int c = 0; c < 4; ++c) {
      float p0 = exp2f(acc[g][c][0]);
      float p1 = exp2f(acc[g][c][1]);
      float p2 = exp2f(acc[g][c][2]);
      float p3 = exp2f(acc[g][c][3]);
      rs[0] += p0; rs[1] += p1; rs[2] += p2; rs[3] += p3;
      csum[c] += (p0 + p1) + (p2 + p3);
    }
    // fold rows across the 16-lane column group (C/D: row=(lane>>4)*4+j)
#pragma unroll
    for (int j = 0; j < 4; ++j) {
      float sv = rs[j];
#pragma unroll
      for (int m = 1; m < 16; m <<= 1) sv += __shfl_xor(sv, m);
      if (l15 == 0) {
        const int row = rowSup + wr * 128 + g * 16 + lhi * 4 + j;
        atomicAdd(&s_sum[row], sv);
      }
    }
  }
  if (offDiag) {
    // mirror: col sums over the wave's 128 rows -> s_sum[col]
#pragma unroll
    for (int c = 0; c < 4; ++c) {
      float cv = csum[c];
      cv += __shfl_xor(cv, 16);
      cv += __shfl_xor(cv, 32);
      if (lhi == 0) {
        const int col = colSup + wc * 64 + c * 16 + l15;
        atomicAdd(&s_sum[col], cv);
      }
    }
  }
}

// ---------------- kernel 3: log(S - diag) - pos, final reduce -------------
__global__ void k_final(const float* __restrict__ s_sum,
                        const float* __restrict__ dacc,
                        const float* __restrict__ pos_val,
                        float* __restrict__ out) {
  __shared__ float red[16];
  float acc = 0.0f;
  for (int r = threadIdx.x; r < kN; r += 1024)
    acc += logf(s_sum[r] - exp2f(dacc[r])) - pos_val[r];
#pragma unroll
  for (int m = 1; m < 64; m <<= 1) acc += __shfl_xor(acc, m);
  const int wave = threadIdx.x >> 6;
  const int lane = threadIdx.x & 63;
  if (lane == 0) red[wave] = acc;
  __syncthreads();
  if (threadIdx.x == 0) {
    float t = 0.0f;
#pragma unroll
    for (int w = 0; w < 16; ++w) t += red[w];
    out[0] = t / (float)kN;
  }
}

extern "C" void kernel_launch(void* const* d_in, const int* in_sizes, int n_in,
                              void* d_out, int out_size, void* d_ws, size_t ws_size,
                              hipStream_t stream) {
  const float* e1 = (const float*)d_in[0];
  const float* e2 = (const float*)d_in[1];
  float* out = (float*)d_out;

  // ws: [zn 4MB][s_sum 32KB][dacc 32KB][pos_val 32KB]
  unsigned short* zn = (unsigned short*)d_ws;
  float* s_sum   = (float*)((char*)d_ws + (size_t)kN * kD * 2);
  float* dacc    = s_sum + kN;
  float* pos_val = dacc + kN;

  hipLaunchKernelGGL(k_normalize, dim3(kN / 4), dim3(256), 0, stream,
                     e1, e2, zn, s_sum);
  hipLaunchKernelGGL(k_pos, dim3(kBH / 4), dim3(256), 0, stream,
                     zn, pos_val, dacc);
  hipLaunchKernelGGL(k_simlse, dim3(kGrid), dim3(512), 0, stream,
                     zn, s_sum);
  hipLaunchKernelGGL(k_final, dim3(1), dim3(1024), 0, stream,
                     s_sum, dacc, pos_val, out);
}

// Round 20
// 79.252 us; speedup vs baseline: 1.0074x; 1.0074x over previous
//
#include <hip/hip_runtime.h>
#include <hip/hip_bf16.h>

// NCE / NT-Xent loss, B=4096, D=256, temp=0.5.
// loss = mean_i( log(sum_{j!=i} exp(sim_ij)) - sim_{i,(i+B)%N} ), N=8192.
// |sim| <= 2 => exp(sim) <= e^2: plain sum(exp), no online max.
//
// R20 = R19 with ONE fix: __launch_bounds__(512,1).
//   R19's launch_bounds(512,2) capped VGPR at 128 while acc[8][4] alone
//   needs 128 -> the ACCUMULATORS spilled to scratch (VGPR=88, MfmaUtil 9%).
//   LDS (96KB) already forces 1 block/CU, so (512,1) costs zero occupancy
//   and restores the design: acc-resident, operands streamed through LDS.
// Structure: triangular 256x256 supertile grid (528 blocks = 51.5% work),
//   3 rotating LDS buffer pairs, counted vmcnt(4) (never 0 in-loop), one
//   barrier per K-step, setprio around MFMA, once-only exp2 + dual fold.
// Algebraic offload (R14): diag stays in row sums, k_final subtracts
//   exp2(||zhat||^2 scaled); pos computed by k_pos as row-pair dots.
//
// Zn stored scaled by sqrt(2*log2(e)) so MFMA output IS the exp2 argument.
// Fragment-tiled Zn: 16-row group g, element (g*16+rr, d), ks=d>>5,
// lhi=(d>>3)&3, dlo=d&7 -> zn[g*4096 + ks*512 + lhi*128 + rr*8 + dlo];
// lane l's fragment ks of group g = 16B at zn + g*4096 + ks*512 + l*8.

constexpr int kN  = 8192;        // 2B rows
constexpr int kD  = 256;         // embedding dim
constexpr int kBH = 4096;        // B
constexpr int kST = 256;         // supertile edge
constexpr int kNRT = kN / kST;   // 32 supertile rows
constexpr int kGrid = kNRT * (kNRT + 1) / 2;   // 528 triangular blocks
constexpr int kKS = kD / 32;     // 8 K-steps (BK=32)
constexpr float kSqrtScale = 1.6986436f;  // sqrt(2*log2(e))
constexpr float kLn2 = 0.6931471805599453f;

typedef __attribute__((ext_vector_type(8))) short bf16x8;  // 4 VGPRs
typedef __attribute__((ext_vector_type(4))) float f32x4;

__device__ __forceinline__ unsigned short f2bf(float f) {
  union { float f; unsigned u; } x;
  x.f = f;
  unsigned u = x.u;
  return (unsigned short)((u + 0x7FFFu + ((u >> 16) & 1u)) >> 16);
}
__device__ __forceinline__ float bf2f(unsigned short h) {
  union { unsigned u; float f; } x;
  x.u = ((unsigned)h) << 16;
  return x.f;
}
__device__ __forceinline__ void gload_lds16(const short* g, short* l) {
  __builtin_amdgcn_global_load_lds(
      (const __attribute__((address_space(1))) void*)g,
      (__attribute__((address_space(3))) void*)l, 16, 0, 0);
}

// ---------------- kernel 1: row-normalize fp32 -> bf16 (tiled + scaled) ---
// Blocks 0..7 zero s_sum; stream order guarantees completion before k_simlse.
__global__ void k_normalize(const float* __restrict__ e1,
                            const float* __restrict__ e2,
                            unsigned short* __restrict__ zn,
                            float* __restrict__ s_sum) {
  if (blockIdx.x < 8) {
    float4 z4 = {0.f, 0.f, 0.f, 0.f};
    *reinterpret_cast<float4*>(s_sum + blockIdx.x * 1024 + threadIdx.x * 4) = z4;
  }
  const int wave = threadIdx.x >> 6;
  const int lane = threadIdx.x & 63;
  const int row  = blockIdx.x * 4 + wave;
  const float* src = (row < kBH) ? (e1 + (size_t)row * kD)
                                 : (e2 + (size_t)(row - kBH) * kD);
  float4 v = *reinterpret_cast<const float4*>(src + lane * 4);
  float ssq = v.x * v.x + v.y * v.y + v.z * v.z + v.w * v.w;
#pragma unroll
  for (int m = 1; m < 64; m <<= 1) ssq += __shfl_xor(ssq, m);
  const float invs = kSqrtScale / sqrtf(ssq);   // eps can never bind (|z|~16)
  ushort4 o;
  o.x = f2bf(v.x * invs);
  o.y = f2bf(v.y * invs);
  o.z = f2bf(v.z * invs);
  o.w = f2bf(v.w * invs);
  const int g  = row >> 4;
  const int rr = row & 15;
  const size_t dst = (size_t)g * 4096 + (lane >> 3) * 512 +
                     ((lane >> 1) & 3) * 128 + rr * 8 + (lane & 1) * 4;
  *reinterpret_cast<ushort4*>(zn + dst) = o;
}

// ---------------- kernel 1b: row-pair dots (pos + diag), 1 wave/pair ------
__global__ void k_pos(const unsigned short* __restrict__ zn,
                      float* __restrict__ pos_val,
                      float* __restrict__ dacc) {
  const int wave = threadIdx.x >> 6;
  const int lane = threadIdx.x & 63;
  const int i = blockIdx.x * 4 + wave;        // 0..4095
  const int j = i + kBH;
  const int rr = i & 15;
  const size_t off = (size_t)(i >> 4) * 4096 + (lane >> 3) * 512 +
                     ((lane >> 1) & 3) * 128 + rr * 8 + (lane & 1) * 4;
  ushort4 ua = *reinterpret_cast<const ushort4*>(zn + off);
  ushort4 ub = *reinterpret_cast<const ushort4*>(zn + off + (size_t)256 * 4096);
  float dij = 0.f, dii = 0.f, djj = 0.f;
  const unsigned short* pa = &ua.x;
  const unsigned short* pb = &ub.x;
#pragma unroll
  for (int q = 0; q < 4; ++q) {
    const float a = bf2f(pa[q]);
    const float b = bf2f(pb[q]);
    dij += a * b;
    dii += a * a;
    djj += b * b;
  }
#pragma unroll
  for (int m = 1; m < 64; m <<= 1) {
    dij += __shfl_xor(dij, m);
    dii += __shfl_xor(dii, m);
    djj += __shfl_xor(djj, m);
  }
  if (lane == 0) {
    const float p = dij * kLn2;   // scaled-dot * ln2 == sim/temp
    pos_val[i] = p;
    pos_val[j] = p;
    dacc[i] = dii;
    dacc[j] = djj;
  }
}

// ---------------- kernel 2: triangular acc-GEMM + exp + dual fold ---------
// Grid: 528 blocks (supertile pairs rt>=ct). Block: 512 thr = 8 waves (2x4);
// wave-tile 128x64 -> acc[8][4] f32x4 (128 VGPR, register-resident under
// the 256-VGPR budget). K-loop: 8 steps of BK=32; A+B K-slices (16KB each)
// staged into 3 rotating LDS buffer pairs with
// { vmcnt(4); barrier; stage(kk+2); compute(kk) } (counted, never 0).
__global__ __launch_bounds__(512, 1)
void k_simlse(const unsigned short* __restrict__ zn,
              float* __restrict__ s_sum) {
  __shared__ __align__(16) short ldsA[3][8192];   // 3 x 16KB A K-slices
  __shared__ __align__(16) short ldsB[3][8192];   // 3 x 16KB B K-slices

  // triangular decode: rt = row supertile, ct <= rt
  const int bid = blockIdx.x;
  int rt = (int)((sqrtf(8.0f * bid + 1.0f) - 1.0f) * 0.5f);
  while ((rt + 1) * (rt + 2) / 2 <= bid) ++rt;
  while (rt * (rt + 1) / 2 > bid) --rt;
  const int ct = bid - rt * (rt + 1) / 2;
  const bool offDiag = (rt != ct);

  const int tid = threadIdx.x;
  const int wave = tid >> 6;      // 0..7
  const int wr = wave >> 2;       // 0..1  row half
  const int wc = wave & 3;        // 0..3  col quarter
  const int lane = tid & 63;
  const int l15 = lane & 15;
  const int lhi = lane >> 4;
  const int rowSup = rt * kST;
  const int colSup = ct * kST;
  const int gA = (rowSup >> 4);   // first 16-row group of A panel
  const int gB = (colSup >> 4);   // first 16-row group of B panel

  // Stage K-step kk (ks = kk&7) into buffer kk%3. Each wave copies 4KB.
  auto stage = [&](int kk) {
    const int ks = kk & 7;
    const int buf = kk % 3;
    const short* zs = (const short*)zn;
    gload_lds16(zs + (size_t)(gA + wave) * 4096 + ks * 512 + lane * 8,
                &ldsA[buf][wave * 512 + lane * 8]);
    gload_lds16(zs + (size_t)(gA + 8 + wave) * 4096 + ks * 512 + lane * 8,
                &ldsA[buf][(8 + wave) * 512 + lane * 8]);
    gload_lds16(zs + (size_t)(gB + wave) * 4096 + ks * 512 + lane * 8,
                &ldsB[buf][wave * 512 + lane * 8]);
    gload_lds16(zs + (size_t)(gB + 8 + wave) * 4096 + ks * 512 + lane * 8,
                &ldsB[buf][(8 + wave) * 512 + lane * 8]);
  };

  f32x4 acc[8][4];
#pragma unroll
  for (int g = 0; g < 8; ++g)
#pragma unroll
    for (int c = 0; c < 4; ++c) acc[g][c] = {0.f, 0.f, 0.f, 0.f};

  stage(0);
  stage(1);
  asm volatile("s_waitcnt vmcnt(0)" ::: "memory");   // exact in-loop counting

#pragma unroll 1
  for (int kk = 0; kk < kKS; ++kk) {
    // steady-state outstanding at top = 8 (stage kk, kk+1); wait slice kk.
    asm volatile("s_waitcnt vmcnt(4)" ::: "memory");
    __builtin_amdgcn_s_barrier();   // all waves have K-slice kk; all done
                                    // reading the buffer stage(kk+2) reuses
    stage(kk + 2);                  // dead wrap at kk>=6 (harmless)

    const short* pA = &ldsA[kk % 3][0];
    const short* pB = &ldsB[kk % 3][0];
    bf16x8 bfr[4];
#pragma unroll
    for (int c = 0; c < 4; ++c)
      bfr[c] = *reinterpret_cast<const bf16x8*>(pB + (wc * 4 + c) * 512 + lane * 8);
    __builtin_amdgcn_s_setprio(1);
#pragma unroll
    for (int g = 0; g < 8; ++g) {
      const bf16x8 afr =
          *reinterpret_cast<const bf16x8*>(pA + (wr * 8 + g) * 512 + lane * 8);
#pragma unroll
      for (int c = 0; c < 4; ++c)
        acc[g][c] = __builtin_amdgcn_mfma_f32_16x16x32_bf16(afr, bfr[c], acc[g][c], 0, 0, 0);
    }
    __builtin_amdgcn_s_setprio(0);
  }

  // ---- epilogue (once): exp2, row fold (always), col fold (offDiag) ----
  float csum[4] = {0.f, 0.f, 0.f, 0.f};
#pragma unroll
  for (int g = 0; g < 8; ++g) {
    float rs[4] = {0.f, 0.f, 0.f, 0.f};
#pragma unroll
    for (int c = 0; c < 4; ++c) {
      float p0 = exp2f(acc[g][c][0]);
      float p1 = exp2f(acc[g][c][1]);
      float p2 = exp2f(acc[g][c][2]);
      float p3 = exp2f(acc[g][c][3]);
      rs[0] += p0; rs[1] += p1; rs[2] += p2; rs[3] += p3;
      csum[c] += (p0 + p1) + (p2 + p3);
    }
    // fold rows across the 16-lane column group (C/D: row=(lane>>4)*4+j)
#pragma unroll
    for (int j = 0; j < 4; ++j) {
      float sv = rs[j];
#pragma unroll
      for (int m = 1; m < 16; m <<= 1) sv += __shfl_xor(sv, m);
      if (l15 == 0) {
        const int row = rowSup + wr * 128 + g * 16 + lhi * 4 + j;
        atomicAdd(&s_sum[row], sv);
      }
    }
  }
  if (offDiag) {
    // mirror: col sums over the wave's 128 rows -> s_sum[col]
#pragma unroll
    for (int c = 0; c < 4; ++c) {
      float cv = csum[c];
      cv += __shfl_xor(cv, 16);
      cv += __shfl_xor(cv, 32);
      if (lhi == 0) {
        const int col = colSup + wc * 64 + c * 16 + l15;
        atomicAdd(&s_sum[col], cv);
      }
    }
  }
}

// ---------------- kernel 3: log(S - diag) - pos, final reduce -------------
__global__ void k_final(const float* __restrict__ s_sum,
                        const float* __restrict__ dacc,
                        const float* __restrict__ pos_val,
                        float* __restrict__ out) {
  __shared__ float red[16];
  float acc = 0.0f;
  for (int r = threadIdx.x; r < kN; r += 1024)
    acc += logf(s_sum[r] - exp2f(dacc[r])) - pos_val[r];
#pragma unroll
  for (int m = 1; m < 64; m <<= 1) acc += __shfl_xor(acc, m);
  const int wave = threadIdx.x >> 6;
  const int lane = threadIdx.x & 63;
  if (lane == 0) red[wave] = acc;
  __syncthreads();
  if (threadIdx.x == 0) {
    float t = 0.0f;
#pragma unroll
    for (int w = 0; w < 16; ++w) t += red[w];
    out[0] = t / (float)kN;
  }
}

extern "C" void kernel_launch(void* const* d_in, const int* in_sizes, int n_in,
                              void* d_out, int out_size, void* d_ws, size_t ws_size,
                              hipStream_t stream) {
  const float* e1 = (const float*)d_in[0];
  const float* e2 = (const float*)d_in[1];
  float* out = (float*)d_out;

  // ws: [zn 4MB][s_sum 32KB][dacc 32KB][pos_val 32KB]
  unsigned short* zn = (unsigned short*)d_ws;
  float* s_sum   = (float*)((char*)d_ws + (size_t)kN * kD * 2);
  float* dacc    = s_sum + kN;
  float* pos_val = dacc + kN;

  hipLaunchKernelGGL(k_normalize, dim3(kN / 4), dim3(256), 0, stream,
                     e1, e2, zn, s_sum);
  hipLaunchKernelGGL(k_pos, dim3(kBH / 4), dim3(256), 0, stream,
                     zn, pos_val, dacc);
  hipLaunchKernelGGL(k_simlse, dim3(kGrid), dim3(512), 0, stream,
                     zn, s_sum);
  hipLaunchKernelGGL(k_final, dim3(1), dim3(1024), 0, stream,
                     s_sum, dacc, pos_val, out);
}

// Round 23
// 79.044 us; speedup vs baseline: 1.0101x; 1.0026x over previous
//
#include <hip/hip_runtime.h>
#include <hip/hip_bf16.h>

// NCE / NT-Xent loss, B=4096, D=256, temp=0.5.
// loss = mean_i( log(sum_{j!=i} exp(sim_ij)) - sim_{i,(i+B)%N} ), N=8192.
// |sim| <= 2 => exp(sim) <= e^2: plain sum(exp), no online max.
//
// R21 = R20 with ONE change: accumulators are 32 NAMED f32x4 variables
//   (q00..q73) instead of f32x4 acc[8][4]. R19/R20 showed VGPR=88 +
//   MfmaUtil 9% regardless of launch bounds: the 2D vector array was
//   demoted to a stack alloca (rule #20, m214 r286 localMem signature),
//   so every MFMA result round-tripped scratch. Named scalars make SROA
//   guaranteed; schedule/grid/LDS/math are byte-identical to R20
//   (which PASSED absmax=0 -> triangular + dual-fold math is verified).
//
// Structure: triangular 256x256 supertile grid (528 blocks = 51.5% work),
//   8 waves (2x4), wave-tile 128x64; both operands stream through 3
//   rotating LDS buffer pairs; { vmcnt(4); barrier; stage(kk+2); compute }
//   counted, never 0 in-loop; setprio around MFMA; exp2 + dual fold once.
// Algebraic offload: diag stays in row sums, k_final subtracts
//   exp2(||zhat||^2 scaled); pos computed by k_pos as row-pair dots.
//
// Zn stored scaled by sqrt(2*log2(e)) so MFMA output IS the exp2 argument.
// Fragment-tiled Zn: 16-row group g, element (g*16+rr, d), ks=d>>5,
// lhi=(d>>3)&3, dlo=d&7 -> zn[g*4096 + ks*512 + lhi*128 + rr*8 + dlo];
// lane l's fragment ks of group g = 16B at zn + g*4096 + ks*512 + l*8.

constexpr int kN  = 8192;        // 2B rows
constexpr int kD  = 256;         // embedding dim
constexpr int kBH = 4096;        // B
constexpr int kST = 256;         // supertile edge
constexpr int kNRT = kN / kST;   // 32 supertile rows
constexpr int kGrid = kNRT * (kNRT + 1) / 2;   // 528 triangular blocks
constexpr int kKS = kD / 32;     // 8 K-steps (BK=32)
constexpr float kSqrtScale = 1.6986436f;  // sqrt(2*log2(e))
constexpr float kLn2 = 0.6931471805599453f;

typedef __attribute__((ext_vector_type(8))) short bf16x8;  // 4 VGPRs
typedef __attribute__((ext_vector_type(4))) float f32x4;

__device__ __forceinline__ unsigned short f2bf(float f) {
  union { float f; unsigned u; } x;
  x.f = f;
  unsigned u = x.u;
  return (unsigned short)((u + 0x7FFFu + ((u >> 16) & 1u)) >> 16);
}
__device__ __forceinline__ float bf2f(unsigned short h) {
  union { unsigned u; float f; } x;
  x.u = ((unsigned)h) << 16;
  return x.f;
}
__device__ __forceinline__ void gload_lds16(const short* g, short* l) {
  __builtin_amdgcn_global_load_lds(
      (const __attribute__((address_space(1))) void*)g,
      (__attribute__((address_space(3))) void*)l, 16, 0, 0);
}

// ---------------- kernel 1: row-normalize fp32 -> bf16 (tiled + scaled) ---
// Blocks 0..7 zero s_sum; stream order guarantees completion before k_simlse.
__global__ void k_normalize(const float* __restrict__ e1,
                            const float* __restrict__ e2,
                            unsigned short* __restrict__ zn,
                            float* __restrict__ s_sum) {
  if (blockIdx.x < 8) {
    float4 z4 = {0.f, 0.f, 0.f, 0.f};
    *reinterpret_cast<float4*>(s_sum + blockIdx.x * 1024 + threadIdx.x * 4) = z4;
  }
  const int wave = threadIdx.x >> 6;
  const int lane = threadIdx.x & 63;
  const int row  = blockIdx.x * 4 + wave;
  const float* src = (row < kBH) ? (e1 + (size_t)row * kD)
                                 : (e2 + (size_t)(row - kBH) * kD);
  float4 v = *reinterpret_cast<const float4*>(src + lane * 4);
  float ssq = v.x * v.x + v.y * v.y + v.z * v.z + v.w * v.w;
#pragma unroll
  for (int m = 1; m < 64; m <<= 1) ssq += __shfl_xor(ssq, m);
  const float invs = kSqrtScale / sqrtf(ssq);   // eps can never bind (|z|~16)
  ushort4 o;
  o.x = f2bf(v.x * invs);
  o.y = f2bf(v.y * invs);
  o.z = f2bf(v.z * invs);
  o.w = f2bf(v.w * invs);
  const int g  = row >> 4;
  const int rr = row & 15;
  const size_t dst = (size_t)g * 4096 + (lane >> 3) * 512 +
                     ((lane >> 1) & 3) * 128 + rr * 8 + (lane & 1) * 4;
  *reinterpret_cast<ushort4*>(zn + dst) = o;
}

// ---------------- kernel 1b: row-pair dots (pos + diag), 1 wave/pair ------
__global__ void k_pos(const unsigned short* __restrict__ zn,
                      float* __restrict__ pos_val,
                      float* __restrict__ dacc) {
  const int wave = threadIdx.x >> 6;
  const int lane = threadIdx.x & 63;
  const int i = blockIdx.x * 4 + wave;        // 0..4095
  const int j = i + kBH;
  const int rr = i & 15;
  const size_t off = (size_t)(i >> 4) * 4096 + (lane >> 3) * 512 +
                     ((lane >> 1) & 3) * 128 + rr * 8 + (lane & 1) * 4;
  ushort4 ua = *reinterpret_cast<const ushort4*>(zn + off);
  ushort4 ub = *reinterpret_cast<const ushort4*>(zn + off + (size_t)256 * 4096);
  float dij = 0.f, dii = 0.f, djj = 0.f;
  const unsigned short* pa = &ua.x;
  const unsigned short* pb = &ub.x;
#pragma unroll
  for (int q = 0; q < 4; ++q) {
    const float a = bf2f(pa[q]);
    const float b = bf2f(pb[q]);
    dij += a * b;
    dii += a * a;
    djj += b * b;
  }
#pragma unroll
  for (int m = 1; m < 64; m <<= 1) {
    dij += __shfl_xor(dij, m);
    dii += __shfl_xor(dii, m);
    djj += __shfl_xor(djj, m);
  }
  if (lane == 0) {
    const float p = dij * kLn2;   // scaled-dot * ln2 == sim/temp
    pos_val[i] = p;
    pos_val[j] = p;
    dacc[i] = dii;
    dacc[j] = djj;
  }
}

// ---------------- kernel 2: triangular acc-GEMM + exp + dual fold ---------
// Grid: 528 blocks (supertile pairs rt>=ct). Block: 512 thr = 8 waves (2x4);
// wave-tile 128x64 -> 32 named f32x4 accumulators (128 VGPR, SSA-resident).
__global__ __launch_bounds__(512, 1)
void k_simlse(const unsigned short* __restrict__ zn,
              float* __restrict__ s_sum) {
  __shared__ __align__(16) short ldsA[3][8192];   // 3 x 16KB A K-slices
  __shared__ __align__(16) short ldsB[3][8192];   // 3 x 16KB B K-slices

  // triangular decode: rt = row supertile, ct <= rt
  const int bid = blockIdx.x;
  int rt = (int)((sqrtf(8.0f * bid + 1.0f) - 1.0f) * 0.5f);
  while ((rt + 1) * (rt + 2) / 2 <= bid) ++rt;
  while (rt * (rt + 1) / 2 > bid) --rt;
  const int ct = bid - rt * (rt + 1) / 2;
  const bool offDiag = (rt != ct);

  const int tid = threadIdx.x;
  const int wave = tid >> 6;      // 0..7
  const int wr = wave >> 2;       // 0..1  row half
  const int wc = wave & 3;        // 0..3  col quarter
  const int lane = tid & 63;
  const int l15 = lane & 15;
  const int lhi = lane >> 4;
  const int rowSup = rt * kST;
  const int colSup = ct * kST;
  const int gA = (rowSup >> 4);   // first 16-row group of A panel
  const int gB = (colSup >> 4);   // first 16-row group of B panel

  // Stage K-step kk (ks = kk&7) into buffer kk%3. Each wave copies 4KB.
  auto stage = [&](int kk) {
    const int ks = kk & 7;
    const int buf = kk % 3;
    const short* zs = (const short*)zn;
    gload_lds16(zs + (size_t)(gA + wave) * 4096 + ks * 512 + lane * 8,
                &ldsA[buf][wave * 512 + lane * 8]);
    gload_lds16(zs + (size_t)(gA + 8 + wave) * 4096 + ks * 512 + lane * 8,
                &ldsA[buf][(8 + wave) * 512 + lane * 8]);
    gload_lds16(zs + (size_t)(gB + wave) * 4096 + ks * 512 + lane * 8,
                &ldsB[buf][wave * 512 + lane * 8]);
    gload_lds16(zs + (size_t)(gB + 8 + wave) * 4096 + ks * 512 + lane * 8,
                &ldsB[buf][(8 + wave) * 512 + lane * 8]);
  };

  // 32 named accumulators: q<g><c>, g=0..7 (row 16-groups), c=0..3 (col).
#define DECL_ACC(g) \
  f32x4 q##g##0 = {0.f,0.f,0.f,0.f}; f32x4 q##g##1 = {0.f,0.f,0.f,0.f}; \
  f32x4 q##g##2 = {0.f,0.f,0.f,0.f}; f32x4 q##g##3 = {0.f,0.f,0.f,0.f};
  DECL_ACC(0) DECL_ACC(1) DECL_ACC(2) DECL_ACC(3)
  DECL_ACC(4) DECL_ACC(5) DECL_ACC(6) DECL_ACC(7)

  stage(0);
  stage(1);
  asm volatile("s_waitcnt vmcnt(0)" ::: "memory");   // exact in-loop counting

#pragma unroll 1
  for (int kk = 0; kk < kKS; ++kk) {
    // steady-state outstanding at top = 8 (stage kk, kk+1); wait slice kk.
    asm volatile("s_waitcnt vmcnt(4)" ::: "memory");
    __builtin_amdgcn_s_barrier();   // all waves have K-slice kk; all done
                                    // reading the buffer stage(kk+2) reuses
    stage(kk + 2);                  // dead wrap at kk>=6 (harmless)

    const short* pA = &ldsA[kk % 3][0];
    const short* pB = &ldsB[kk % 3][0];
    const bf16x8 bfr0 = *reinterpret_cast<const bf16x8*>(pB + (wc * 4 + 0) * 512 + lane * 8);
    const bf16x8 bfr1 = *reinterpret_cast<const bf16x8*>(pB + (wc * 4 + 1) * 512 + lane * 8);
    const bf16x8 bfr2 = *reinterpret_cast<const bf16x8*>(pB + (wc * 4 + 2) * 512 + lane * 8);
    const bf16x8 bfr3 = *reinterpret_cast<const bf16x8*>(pB + (wc * 4 + 3) * 512 + lane * 8);
    __builtin_amdgcn_s_setprio(1);
#define MFMA_G(g) { \
    const bf16x8 afr = *reinterpret_cast<const bf16x8*>(pA + (wr * 8 + g) * 512 + lane * 8); \
    q##g##0 = __builtin_amdgcn_mfma_f32_16x16x32_bf16(afr, bfr0, q##g##0, 0, 0, 0); \
    q##g##1 = __builtin_amdgcn_mfma_f32_16x16x32_bf16(afr, bfr1, q##g##1, 0, 0, 0); \
    q##g##2 = __builtin_amdgcn_mfma_f32_16x16x32_bf16(afr, bfr2, q##g##2, 0, 0, 0); \
    q##g##3 = __builtin_amdgcn_mfma_f32_16x16x32_bf16(afr, bfr3, q##g##3, 0, 0, 0); }
    MFMA_G(0) MFMA_G(1) MFMA_G(2) MFMA_G(3)
    MFMA_G(4) MFMA_G(5) MFMA_G(6) MFMA_G(7)
    __builtin_amdgcn_s_setprio(0);
  }

  // ---- epilogue (once): exp2, row fold (always), col fold (offDiag) ----
  float cs0 = 0.f, cs1 = 0.f, cs2 = 0.f, cs3 = 0.f;
#define EPI_C(g,c) { \
    float p0 = exp2f(q##g##c[0]); float p1 = exp2f(q##g##c[1]); \
    float p2 = exp2f(q##g##c[2]); float p3 = exp2f(q##g##c[3]); \
    rs0 += p0; rs1 += p1; rs2 += p2; rs3 += p3; \
    cs##c += (p0 + p1) + (p2 + p3); }
#define ROW_FOLD(g,j,v) { float sv = v; \
    sv += __shfl_xor(sv, 1); sv += __shfl_xor(sv, 2); \
    sv += __shfl_xor(sv, 4); sv += __shfl_xor(sv, 8); \
    if (l15 == 0) \
      atomicAdd(&s_sum[rowSup + wr * 128 + g * 16 + lhi * 4 + j], sv); }
#define EPI_G(g) { float rs0 = 0.f, rs1 = 0.f, rs2 = 0.f, rs3 = 0.f; \
    EPI_C(g,0) EPI_C(g,1) EPI_C(g,2) EPI_C(g,3) \
    ROW_FOLD(g,0,rs0) ROW_FOLD(g,1,rs1) ROW_FOLD(g,2,rs2) ROW_FOLD(g,3,rs3) }
  EPI_G(0) EPI_G(1) EPI_G(2) EPI_G(3)
  EPI_G(4) EPI_G(5) EPI_G(6) EPI_G(7)

  if (offDiag) {
    // mirror: col sums over the wave's 128 rows -> s_sum[col]
#define COL_FOLD(c) { float cv = cs##c; \
    cv += __shfl_xor(cv, 16); cv += __shfl_xor(cv, 32); \
    if (lhi == 0) \
      atomicAdd(&s_sum[colSup + wc * 64 + c * 16 + l15], cv); }
    COL_FOLD(0) COL_FOLD(1) COL_FOLD(2) COL_FOLD(3)
  }
}

// ---------------- kernel 3: log(S - diag) - pos, final reduce -------------
__global__ void k_final(const float* __restrict__ s_sum,
                        const float* __restrict__ dacc,
                        const float* __restrict__ pos_val,
                        float* __restrict__ out) {
  __shared__ float red[16];
  float acc = 0.0f;
  for (int r = threadIdx.x; r < kN; r += 1024)
    acc += logf(s_sum[r] - exp2f(dacc[r])) - pos_val[r];
#pragma unroll
  for (int m = 1; m < 64; m <<= 1) acc += __shfl_xor(acc, m);
  const int wave = threadIdx.x >> 6;
  const int lane = threadIdx.x & 63;
  if (lane == 0) red[wave] = acc;
  __syncthreads();
  if (threadIdx.x == 0) {
    float t = 0.0f;
#pragma unroll
    for (int w = 0; w < 16; ++w) t += red[w];
    out[0] = t / (float)kN;
  }
}

extern "C" void kernel_launch(void* const* d_in, const int* in_sizes, int n_in,
                              void* d_out, int out_size, void* d_ws, size_t ws_size,
                              hipStream_t stream) {
  const float* e1 = (const float*)d_in[0];
  const float* e2 = (const float*)d_in[1];
  float* out = (float*)d_out;

  // ws: [zn 4MB][s_sum 32KB][dacc 32KB][pos_val 32KB]
  unsigned short* zn = (unsigned short*)d_ws;
  float* s_sum   = (float*)((char*)d_ws + (size_t)kN * kD * 2);
  float* dacc    = s_sum + kN;
  float* pos_val = dacc + kN;

  hipLaunchKernelGGL(k_normalize, dim3(kN / 4), dim3(256), 0, stream,
                     e1, e2, zn, s_sum);
  hipLaunchKernelGGL(k_pos, dim3(kBH / 4), dim3(256), 0, stream,
                     zn, pos_val, dacc);
  hipLaunchKernelGGL(k_simlse, dim3(kGrid), dim3(512), 0, stream,
                     zn, s_sum);
  hipLaunchKernelGGL(k_final, dim3(1), dim3(1024), 0, stream,
                     s_sum, dacc, pos_val, out);
}

// Round 24
// 53.198 us; speedup vs baseline: 1.5008x; 1.4858x over previous
//
#include <hip/hip_runtime.h>
#include <hip/hip_bf16.h>

// NCE / NT-Xent loss, B=4096, D=256, temp=0.5.
// loss = mean_i( log(sum_{j!=i} exp(sim_ij)) - sim_{i,(i+B)%N} ), N=8192.
// |sim| <= 2 => exp(sim) <= e^2: plain sum(exp), no online max.
//
// FINAL (revert to R18, best verified: 53.1us total).
// R18: SYMMETRY — sim is symmetric, so only the upper-triangle tiles are
// computed (2080 of 4096 128x128 blocks). Off-diagonal blocks fold each
// exp value into BOTH the row sums (row axis) and, via sim_ij = sim_ji,
// the row sums of the column range (column axis, folded through LDS).
// Diagonal blocks fold rows only. ~51% of the full MFMA/LDS/exp work.
// Loop structure = R17: 4-buffer rotating LDS-B, single barrier per tile,
// counted vmcnt (never 0 in-loop), branch-free epilogue, setprio on MFMA.
// Algebraic offload (R14): diag stays in row sums, k_final subtracts
// exp2(||zhat||^2 scaled); pos computed by k_pos as row-pair dots.
//
// R19-R23 epilogue: the acc-dominant 256x256 1-block/CU structure was
// tried with 3 single-variable fixes (launch bounds, named accs); all
// null at 73.5us / MfmaUtil 9% -> reverted per pre-registered falsifier.
//
// Zn stored scaled by sqrt(2*log2(e)) so MFMA output IS the exp2 argument.
// Fragment-tiled Zn: 16-row group g, element (g*16+rr, d), ks=d>>5,
// lhi=(d>>3)&3, dlo=d&7 -> zn[g*4096 + ks*512 + lhi*128 + rr*8 + dlo];
// lane l's fragment ks of group g = 16B at zn + g*4096 + ks*512 + l*8.

constexpr int kN  = 8192;        // 2B rows
constexpr int kD  = 256;         // embedding dim
constexpr int kBH = 4096;        // B
constexpr int kTile = 128;       // block tile: 128x128
constexpr int kNT = kTile / 16;  // 8 column sub-tiles per block
constexpr int kGrid = 64 * 32 + 32;  // triangular grid: 2080 blocks
constexpr float kSqrtScale = 1.6986436f;  // sqrt(2*log2(e))
constexpr float kLn2 = 0.6931471805599453f;

typedef __attribute__((ext_vector_type(8))) short bf16x8;  // 4 VGPRs
typedef __attribute__((ext_vector_type(4))) float f32x4;

__device__ __forceinline__ unsigned short f2bf(float f) {
  union { float f; unsigned u; } x;
  x.f = f;
  unsigned u = x.u;
  return (unsigned short)((u + 0x7FFFu + ((u >> 16) & 1u)) >> 16);
}
__device__ __forceinline__ float bf2f(unsigned short h) {
  union { unsigned u; float f; } x;
  x.u = ((unsigned)h) << 16;
  return x.f;
}
__device__ __forceinline__ void gload_lds16(const short* g, short* l) {
  __builtin_amdgcn_global_load_lds(
      (const __attribute__((address_space(1))) void*)g,
      (__attribute__((address_space(3))) void*)l, 16, 0, 0);
}

// ---------------- kernel 1: row-normalize fp32 -> bf16 (tiled + scaled) ---
// Blocks 0..7 zero s_sum; stream order guarantees completion before k_simlse.
__global__ void k_normalize(const float* __restrict__ e1,
                            const float* __restrict__ e2,
                            unsigned short* __restrict__ zn,
                            float* __restrict__ s_sum) {
  if (blockIdx.x < 8) {
    float4 z4 = {0.f, 0.f, 0.f, 0.f};
    *reinterpret_cast<float4*>(s_sum + blockIdx.x * 1024 + threadIdx.x * 4) = z4;
  }
  const int wave = threadIdx.x >> 6;
  const int lane = threadIdx.x & 63;
  const int row  = blockIdx.x * 4 + wave;
  const float* src = (row < kBH) ? (e1 + (size_t)row * kD)
                                 : (e2 + (size_t)(row - kBH) * kD);
  float4 v = *reinterpret_cast<const float4*>(src + lane * 4);
  float ssq = v.x * v.x + v.y * v.y + v.z * v.z + v.w * v.w;
#pragma unroll
  for (int m = 1; m < 64; m <<= 1) ssq += __shfl_xor(ssq, m);
  const float invs = kSqrtScale / sqrtf(ssq);   // eps can never bind (|z|~16)
  ushort4 o;
  o.x = f2bf(v.x * invs);
  o.y = f2bf(v.y * invs);
  o.z = f2bf(v.z * invs);
  o.w = f2bf(v.w * invs);
  const int g  = row >> 4;
  const int rr = row & 15;
  const size_t dst = (size_t)g * 4096 + (lane >> 3) * 512 +
                     ((lane >> 1) & 3) * 128 + rr * 8 + (lane & 1) * 4;
  *reinterpret_cast<ushort4*>(zn + dst) = o;
}

// ---------------- kernel 1b: row-pair dots (pos + diag), 1 wave/pair ------
__global__ void k_pos(const unsigned short* __restrict__ zn,
                      float* __restrict__ pos_val,
                      float* __restrict__ dacc) {
  const int wave = threadIdx.x >> 6;
  const int lane = threadIdx.x & 63;
  const int i = blockIdx.x * 4 + wave;        // 0..4095
  const int j = i + kBH;
  const int rr = i & 15;
  const size_t off = (size_t)(i >> 4) * 4096 + (lane >> 3) * 512 +
                     ((lane >> 1) & 3) * 128 + rr * 8 + (lane & 1) * 4;
  ushort4 ua = *reinterpret_cast<const ushort4*>(zn + off);
  ushort4 ub = *reinterpret_cast<const ushort4*>(zn + off + (size_t)256 * 4096);
  float dij = 0.f, dii = 0.f, djj = 0.f;
  const unsigned short* pa = &ua.x;
  const unsigned short* pb = &ub.x;
#pragma unroll
  for (int q = 0; q < 4; ++q) {
    const float a = bf2f(pa[q]);
    const float b = bf2f(pb[q]);
    dij += a * b;
    dii += a * a;
    djj += b * b;
  }
#pragma unroll
  for (int m = 1; m < 64; m <<= 1) {
    dij += __shfl_xor(dij, m);
    dii += __shfl_xor(dii, m);
    djj += __shfl_xor(djj, m);
  }
  if (lane == 0) {
    const float p = dij * kLn2;   // scaled-dot * ln2 == sim/temp
    pos_val[i] = p;
    pos_val[j] = p;
    dacc[i] = dii;
    dacc[j] = djj;
  }
}

// ---------------- kernel 2: triangular GEMM + exp + dual-axis fold --------
// Triangular grid (2080 blocks): bid<2048 -> rt=bid>>5, ct=(rt+(bid&31))&63
// (x=0 gives the 64 diagonal blocks); bid>=2048 -> rt=bid-2048, ct=rt+32.
// Each unordered 128x128 tile pair appears exactly once.
// Block: 4 waves x 32 rows. Per sub-tile (16 cols): vmcnt(4); barrier;
// stage(t+3); ds_read+MFMA+exp; fold rows (regs) and cols (LDS).
__global__ __launch_bounds__(256, 4)
void k_simlse(const unsigned short* __restrict__ zn,
              float* __restrict__ s_sum) {
  __shared__ __align__(16) short ldsB[4][4096];   // 4 rotating 8KB tiles
  __shared__ float ldsCol[4][kTile];              // per-wave column sums

  const int bid = blockIdx.x;
  int rt, ct;
  if (bid < 2048) {
    rt = bid >> 5;
    ct = (rt + (bid & 31)) & 63;
  } else {
    rt = bid - 2048;
    ct = rt + 32;
  }
  const bool offDiag = (rt != ct);
  const int wave = threadIdx.x >> 6;
  const int lane = threadIdx.x & 63;
  const int l15 = lane & 15;
  const int lhi = lane >> 4;
  const int rowBase = rt * kTile + wave * 32;
  const int grpBase = ct * kNT;   // first 16-col group of this col-panel

  // ---- A fragments (2 groups = 32 rows) ----
  bf16x8 a0[8], a1[8];
  {
    const unsigned short* ap = zn + (size_t)(rowBase >> 4) * 4096 + lane * 8;
#pragma unroll
    for (int ks = 0; ks < 8; ++ks) {
      a0[ks] = *reinterpret_cast<const bf16x8*>(ap + ks * 512);
      a1[ks] = *reinterpret_cast<const bf16x8*>(ap + 4096 + ks * 512);
    }
  }

  // Stage sub-tile (t&7) into buffer (t&3); each wave copies its 2KB slice.
  auto stage = [&](int t) {
    const short* src = (const short*)zn +
                       (size_t)(grpBase + (t & (kNT - 1))) * 4096 + wave * 1024;
    short* dst = &ldsB[t & 3][wave * 1024];
    gload_lds16(src + lane * 8, dst);
    gload_lds16(src + 512 + lane * 8, dst + 512);
  };

  stage(0);
  stage(1);
  stage(2);
  // Drain A-loads AND prologue stages: exact in-loop vmcnt counting.
  asm volatile("s_waitcnt vmcnt(0)" ::: "memory");

  float sacc[2][4] = {{0.f,0.f,0.f,0.f},{0.f,0.f,0.f,0.f}};

#pragma unroll 1
  for (int t = 0; t < kNT; ++t) {
    // Tile t resident when <=4 stage-loads outstanding (tiles t+1, t+2).
    asm volatile("s_waitcnt vmcnt(4)" ::: "memory");
    __builtin_amdgcn_s_barrier();   // tile t visible; all waves done with t-1
    stage(t + 3);                   // overwrites tile t-1's buffer (safe)

    const short* bt = &ldsB[t & 3][0];
    bf16x8 b[8];
#pragma unroll
    for (int ks = 0; ks < 8; ++ks)
      b[ks] = *reinterpret_cast<const bf16x8*>(bt + ks * 512 + lane * 8);

    f32x4 acc0 = {0.f,0.f,0.f,0.f};
    f32x4 acc1 = {0.f,0.f,0.f,0.f};
    __builtin_amdgcn_s_setprio(1);
#pragma unroll
    for (int ks = 0; ks < 8; ++ks) {
      acc0 = __builtin_amdgcn_mfma_f32_16x16x32_bf16(a0[ks], b[ks], acc0, 0, 0, 0);
      acc1 = __builtin_amdgcn_mfma_f32_16x16x32_bf16(a1[ks], b[ks], acc1, 0, 0, 0);
    }
    __builtin_amdgcn_s_setprio(0);

    // branch-free epilogue: 8 exp2; row fold in regs, col fold via shfl+LDS
    float p0[4], p1[4];
#pragma unroll
    for (int j = 0; j < 4; ++j) {
      p0[j] = exp2f(acc0[j]);
      p1[j] = exp2f(acc1[j]);
      sacc[0][j] += p0[j];
      sacc[1][j] += p1[j];
    }
    float cs = ((p0[0] + p0[1]) + (p0[2] + p0[3])) +
               ((p1[0] + p1[1]) + (p1[2] + p1[3]));
    cs += __shfl_xor(cs, 16);
    cs += __shfl_xor(cs, 32);          // lanes with lhi==0: col sum of 32 rows
    if (lhi == 0) ldsCol[wave][t * 16 + l15] = cs;  // each col written once
  }

  // ---- row fold across the 16-lane column group; l15==0 lanes own rows ----
#pragma unroll
  for (int s = 0; s < 2; ++s) {
#pragma unroll
    for (int j = 0; j < 4; ++j) {
      float sv = sacc[s][j];
#pragma unroll
      for (int m = 1; m < 16; m <<= 1) sv += __shfl_xor(sv, m);
      if (l15 == 0) {
        const int row = rowBase + s * 16 + lhi * 4 + j;
        atomicAdd(&s_sum[row], sv);
      }
    }
  }

  // ---- mirror fold: col sums -> row sums of the column range -------------
  if (offDiag) {
    __syncthreads();   // all waves' ldsCol written
    for (int c = threadIdx.x; c < kTile; c += 256) {
      const float v = (ldsCol[0][c] + ldsCol[1][c]) +
                      (ldsCol[2][c] + ldsCol[3][c]);
      atomicAdd(&s_sum[ct * kTile + c], v);
    }
  }
}

// ---------------- kernel 3: log(S - diag) - pos, final reduce -------------
__global__ void k_final(const float* __restrict__ s_sum,
                        const float* __restrict__ dacc,
                        const float* __restrict__ pos_val,
                        float* __restrict__ out) {
  __shared__ float red[16];
  float acc = 0.0f;
  for (int r = threadIdx.x; r < kN; r += 1024)
    acc += logf(s_sum[r] - exp2f(dacc[r])) - pos_val[r];
#pragma unroll
  for (int m = 1; m < 64; m <<= 1) acc += __shfl_xor(acc, m);
  const int wave = threadIdx.x >> 6;
  const int lane = threadIdx.x & 63;
  if (lane == 0) red[wave] = acc;
  __syncthreads();
  if (threadIdx.x == 0) {
    float t = 0.0f;
#pragma unroll
    for (int w = 0; w < 16; ++w) t += red[w];
    out[0] = t / (float)kN;
  }
}

extern "C" void kernel_launch(void* const* d_in, const int* in_sizes, int n_in,
                              void* d_out, int out_size, void* d_ws, size_t ws_size,
                              hipStream_t stream) {
  const float* e1 = (const float*)d_in[0];
  const float* e2 = (const float*)d_in[1];
  float* out = (float*)d_out;

  // ws: [zn 4MB][s_sum 32KB][dacc 32KB][pos_val 32KB]
  unsigned short* zn = (unsigned short*)d_ws;
  float* s_sum   = (float*)((char*)d_ws + (size_t)kN * kD * 2);
  float* dacc    = s_sum + kN;
  float* pos_val = dacc + kN;

  hipLaunchKernelGGL(k_normalize, dim3(kN / 4), dim3(256), 0, stream,
                     e1, e2, zn, s_sum);
  hipLaunchKernelGGL(k_pos, dim3(kBH / 4), dim3(256), 0, stream,
                     zn, pos_val, dacc);
  hipLaunchKernelGGL(k_simlse, dim3(kGrid), dim3(256), 0, stream,
                     zn, s_sum);
  hipLaunchKernelGGL(k_final, dim3(1), dim3(1024), 0, stream,
                     s_sum, dacc, pos_val, out);
}